// Round 1
// baseline (1075.654 us; speedup 1.0000x reference)
//
#include <hip/hip_runtime.h>
#include <cstdint>
#include <cstddef>

// LSTM B=256,S=512,C=64,H=128, 2 layers, gates i,f,g,o (torch order).
// Round 4: FUSED both layers into one kernel, 32 blocks x 512 threads.
// Skewed pipeline: iteration k computes L0's h0_k AND L1's h1_{k-1}; both
// read only previous-iteration LDS buffers -> independent within an iter,
// ONE lgkmcnt-only barrier per iter (no vmcnt drain -> prefetch spans the
// barrier). No inter-block traffic at all (no y1 store, no threadfence,
// no flag spins). L0's input GEMM (x@Wih0^T + b) is hoisted into a
// throughput prep kernel writing a per-lane-packed bf16 stream (xg),
// freeing ~48 VGPRs so all three weight matrices (192 VGPRs of B-frags)
// stay register-resident under the 256-VGPR / 2-wave-per-SIMD cap.
//
// MFMA 16x16x32 bf16 frags (verified rounds 1-3):
//   A[m=lane&15][k=(lane>>4)*8+j], B == W[n=lane&15][k] 16B row chunk,
//   D[m=4*(lane>>4)+reg][n=lane&15]
// Batch rows permuted into tile rows {m : (m&3)<2}: elementwise touches
// rr=0,1 only (2 rows/lane).

#define S_LEN 512
#define B_SZ  256
#define C_IN  64
#define HDIM  128
#define XG_TSTRIDE (32 * 512 * 8)   // shorts per timestep slot of xg

using short8  = __attribute__((ext_vector_type(8))) short;   // 8 bf16
using float4v = __attribute__((ext_vector_type(4))) float;

template<bool V> struct Flag { static constexpr bool value = V; };

__device__ __forceinline__ unsigned short f2b(float f) {
    union { float f; unsigned int u; } v; v.f = f;
    unsigned int u = v.u;
    return (unsigned short)((u + 0x7FFFu + ((u >> 16) & 1u)) >> 16);
}
__device__ __forceinline__ float b2f(unsigned short s) {
    union { unsigned int u; float f; } v; v.u = ((unsigned int)s) << 16;
    return v.f;
}
// lean activations: sigma = rcp(1+exp2(-x*log2e)), tanh = 1-2*rcp(1+exp2(2x*log2e))
__device__ __forceinline__ float sig_(float x) {
    return __builtin_amdgcn_rcpf(1.0f + __builtin_amdgcn_exp2f(x * -1.442695041f));
}
__device__ __forceinline__ float tanh_(float x) {
    return 1.0f - 2.0f * __builtin_amdgcn_rcpf(1.0f + __builtin_amdgcn_exp2f(x * 2.885390082f));
}
__device__ __forceinline__ short8 load8_f2b(const float* s) {
    const float4v f0 = *(const float4v*)s;
    const float4v f1 = *(const float4v*)(s + 4);
    short8 t;
#pragma unroll
    for (int e = 0; e < 4; ++e) {
        t[e]     = (short)f2b(f0[e]);
        t[e + 4] = (short)f2b(f1[e]);
    }
    return t;
}

// ---- weight conversion (fp32 -> bf16 B-frag-readable row-major) ----
__global__ void conv_kernel(const float* __restrict__ whh0,
                            const float* __restrict__ wih1, const float* __restrict__ whh1,
                            const float* __restrict__ bih1, const float* __restrict__ bhh1,
                            unsigned short* __restrict__ whh0_b, unsigned short* __restrict__ wih1_b,
                            unsigned short* __restrict__ whh1_b, float* __restrict__ bias1) {
    int i = blockIdx.x * blockDim.x + threadIdx.x;
    if (i < 4 * HDIM * HDIM) {
        whh0_b[i] = f2b(whh0[i]);
        wih1_b[i] = f2b(wih1[i]);
        whh1_b[i] = f2b(whh1[i]);
    }
    if (i < 4 * HDIM) bias1[i] = bih1[i] + bhh1[i];
}

// ---- hoisted L0 input GEMM: xg[t][blk][tid][8] = (x@Wih0^T + bih0 + bhh0),
//      packed per-lane in D-layout order [g*2+rr] so the recurrent kernel's
//      lane (same blk,tid mapping) loads its 8 acc-init values as one 16B read.
__global__ __launch_bounds__(512, 2)
void xg_gemm(const float* __restrict__ x, const float* __restrict__ wih0,
             const float* __restrict__ bih0, const float* __restrict__ bhh0,
             unsigned short* __restrict__ xg) {
    const int tid = threadIdx.x;
    const int w = tid >> 6, L = tid & 63, q = L >> 4, r = L & 15;
    const int blk = blockIdx.x, tch = blockIdx.y;
    const int boff = blk * 8, j = w * 16 + r;
    const int rowload = (r >> 2) * 2 + (r & 1);

    short8 wf[4][2]; float bias_s[4];
#pragma unroll
    for (int g = 0; g < 4; ++g) {
        const int nrow = g * HDIM + j;
#pragma unroll
        for (int kk = 0; kk < 2; ++kk)
            wf[g][kk] = load8_f2b(wih0 + (size_t)nrow * C_IN + kk * 32 + q * 8);
        bias_s[g] = bih0[nrow] + bhh0[nrow];
    }

    const float* px = x + ((size_t)(boff + rowload) * S_LEN + (size_t)tch * 32) * C_IN + q * 8;
    unsigned short* po = xg + ((size_t)(tch * 32) * 32 + blk) * 4096 + (size_t)tid * 8;

    for (int tt = 0; tt < 32; ++tt) {
        short8 xa[2];
#pragma unroll
        for (int kk = 0; kk < 2; ++kk) xa[kk] = load8_f2b(px + kk * 32);
        float4v a[4];
#pragma unroll
        for (int g = 0; g < 4; ++g) a[g] = (float4v){bias_s[g], bias_s[g], 0.f, 0.f};
#pragma unroll
        for (int kk = 0; kk < 2; ++kk)
#pragma unroll
            for (int g = 0; g < 4; ++g)
                a[g] = __builtin_amdgcn_mfma_f32_16x16x32_bf16(xa[kk], wf[g][kk], a[g], 0, 0, 0);
        short8 o;
#pragma unroll
        for (int g = 0; g < 4; ++g) {
            o[2 * g]     = (short)f2b(a[g][0]);
            o[2 * g + 1] = (short)f2b(a[g][1]);
        }
        *(short8*)po = o;
        px += C_IN;
        po += XG_TSTRIDE;
    }
}

// ---- fused 2-layer recurrence ----
__global__ __launch_bounds__(512, 2)
void lstm_fused(const unsigned short* __restrict__ whh0_b,
                const unsigned short* __restrict__ wih1_b,
                const unsigned short* __restrict__ whh1_b,
                const float* __restrict__ bias1,
                const unsigned short* __restrict__ xg,
                float* __restrict__ out) {
    // LDS: h0 double-buffer + h1 double-buffer, each 2048 shorts (16 rows x 128 cols)
    __shared__ __align__(16) unsigned short hbuf[4 * 2048];
    const int tid = threadIdx.x;
    const int w = tid >> 6, L = tid & 63, q = L >> 4, r = L & 15;
    const int blk = blockIdx.x;
    const int boff = blk * 8, j = w * 16 + r;

    // register-resident weights: 48 B-frags = 192 VGPRs
    short8 whh0[4][4], wih1[4][4], whh1[4][4];
    float b1s[4];
#pragma unroll
    for (int g = 0; g < 4; ++g) {
        const size_t nrow = (size_t)(g * HDIM + j);
#pragma unroll
        for (int kk = 0; kk < 4; ++kk) {
            whh0[g][kk] = *(const short8*)(whh0_b + nrow * HDIM + kk * 32 + q * 8);
            wih1[g][kk] = *(const short8*)(wih1_b + nrow * HDIM + kk * 32 + q * 8);
            whh1[g][kk] = *(const short8*)(whh1_b + nrow * HDIM + kk * 32 + q * 8);
        }
        b1s[g] = bias1[g * HDIM + j];
    }

    for (int idx = tid; idx < 4 * 1024; idx += 512) ((unsigned int*)hbuf)[idx] = 0u;

    float cf0[2] = {0.f, 0.f}, cf1[2] = {0.f, 0.f};
    const int chunkbase = (j >> 3) * 128 + (j & 7);     // h write slot (col-chunk layout)
    const int rdoff = q * 128 + r * 8;                  // A-frag read: + kk*512
    float* fout = out + (size_t)(boff + 2 * q) * HDIM + j;

    const unsigned short* pxg = xg + (size_t)blk * 4096 + (size_t)tid * 8;
    short8 xgA = *(const short8*)pxg;   // xg[t=0]
    pxg += XG_TSTRIDE;
    short8 xgB;

    __syncthreads();    // covers LDS zero + weight/xg load drain (once, cold)

    // iteration k: L0 h0_k (if D0), L1 h1_{k-1} (if D1). Reads r0/r1, writes w0/w1.
    auto step = [&](auto D0_, auto D1_, auto FIN_,
                    unsigned short* r0, unsigned short* w0,
                    unsigned short* r1, unsigned short* w1,
                    short8& xc, short8& xn) {
        constexpr bool D0  = decltype(D0_)::value;
        constexpr bool D1  = decltype(D1_)::value;
        constexpr bool FIN = decltype(FIN_)::value;

        if constexpr (!FIN) {            // prefetch next xg (vmcnt load, spans the barrier)
            xn = *(const short8*)pxg;
            pxg += XG_TSTRIDE;
        }

        float4v a0[4], a1[4];
        if constexpr (D0) {
#pragma unroll
            for (int g = 0; g < 4; ++g)
                a0[g] = (float4v){b2f((unsigned short)xc[2 * g]),
                                  b2f((unsigned short)xc[2 * g + 1]), 0.f, 0.f};
        }
        if constexpr (D1) {
#pragma unroll
            for (int g = 0; g < 4; ++g) a1[g] = (float4v){b1s[g], b1s[g], 0.f, 0.f};
        }

        // shared A-frag: h0_{k-1} feeds BOTH L0-hh and L1-ih (8 indep 4-deep chains)
#pragma unroll
        for (int kk = 0; kk < 4; ++kk) {
            const short8 h0f = *(const short8*)(r0 + kk * 512 + rdoff);
            if constexpr (D0)
#pragma unroll
                for (int g = 0; g < 4; ++g)
                    a0[g] = __builtin_amdgcn_mfma_f32_16x16x32_bf16(h0f, whh0[g][kk], a0[g], 0, 0, 0);
            if constexpr (D1)
#pragma unroll
                for (int g = 0; g < 4; ++g)
                    a1[g] = __builtin_amdgcn_mfma_f32_16x16x32_bf16(h0f, wih1[g][kk], a1[g], 0, 0, 0);
        }

        // L0 elementwise early: frees a0 before the L1-hh MFMAs, VALU co-issues with MFMA
        if constexpr (D0) {
#pragma unroll
            for (int rr = 0; rr < 2; ++rr) {
                const float iv = sig_(a0[0][rr]);
                const float fv = sig_(a0[1][rr]);
                const float gv = tanh_(a0[2][rr]);
                const float ov = sig_(a0[3][rr]);
                cf0[rr] = fv * cf0[rr] + iv * gv;
                w0[chunkbase + (4 * q + rr) * 8] = f2b(ov * tanh_(cf0[rr]));
            }
        }

        if constexpr (D1) {
#pragma unroll
            for (int kk = 0; kk < 4; ++kk) {
                const short8 h1f = *(const short8*)(r1 + kk * 512 + rdoff);
#pragma unroll
                for (int g = 0; g < 4; ++g)
                    a1[g] = __builtin_amdgcn_mfma_f32_16x16x32_bf16(h1f, whh1[g][kk], a1[g], 0, 0, 0);
            }
#pragma unroll
            for (int rr = 0; rr < 2; ++rr) {
                const float iv = sig_(a1[0][rr]);
                const float fv = sig_(a1[1][rr]);
                const float gv = tanh_(a1[2][rr]);
                const float ov = sig_(a1[3][rr]);
                cf1[rr] = fv * cf1[rr] + iv * gv;
                const float hv = ov * tanh_(cf1[rr]);
                if constexpr (FIN) fout[rr * HDIM] = hv;
                else w1[chunkbase + (4 * q + rr) * 8] = f2b(hv);
            }
        }

        // lgkm-only barrier: h_t visible, but vmcnt (xg prefetch) stays in flight
        if constexpr (!FIN)
            asm volatile("s_waitcnt lgkmcnt(0)\n\ts_barrier" ::: "memory");
    };

    unsigned short* h0A = hbuf;
    unsigned short* h0B = hbuf + 2048;
    unsigned short* h1A = hbuf + 4096;
    unsigned short* h1B = hbuf + 6144;
    using T = Flag<true>; using F = Flag<false>;

    step(T{}, F{}, F{}, h0A, h0B, h1A, h1B, xgA, xgB);      // k=0: L0 only
#pragma unroll 1
    for (int k = 0; k < 255; ++k) {                          // k=1..510
        step(T{}, T{}, F{}, h0B, h0A, h1B, h1A, xgB, xgA);
        step(T{}, T{}, F{}, h0A, h0B, h1A, h1B, xgA, xgB);
    }
    step(T{}, T{}, F{}, h0B, h0A, h1B, h1A, xgB, xgA);      // k=511
    step(F{}, T{}, T{}, h0A, h0B, h1A, h1B, xgA, xgB);      // k=512: L1 only -> out
}

// ---- workspace layout (bytes) ----
//        0 : whh0_b 131072
//   131072 : wih1_b 131072
//   262144 : whh1_b 131072
//   393216 : bias1    2048
//   524288 : xg   134742016   ((S_LEN+2) t-slots: 2 pad slots for tail prefetch)
// total ~135.3 MB

extern "C" void kernel_launch(void* const* d_in, const int* in_sizes, int n_in,
                              void* d_out, int out_size, void* d_ws, size_t ws_size,
                              hipStream_t stream) {
    const float* x    = (const float*)d_in[0];
    const float* wih0 = (const float*)d_in[1];
    const float* whh0 = (const float*)d_in[2];
    const float* bih0 = (const float*)d_in[3];
    const float* bhh0 = (const float*)d_in[4];
    const float* wih1 = (const float*)d_in[5];
    const float* whh1 = (const float*)d_in[6];
    const float* bih1 = (const float*)d_in[7];
    const float* bhh1 = (const float*)d_in[8];

    char* ws = (char*)d_ws;
    unsigned short* whh0_b = (unsigned short*)(ws + 0);
    unsigned short* wih1_b = (unsigned short*)(ws + 131072);
    unsigned short* whh1_b = (unsigned short*)(ws + 262144);
    float*          bias1  = (float*)(ws + 393216);
    unsigned short* xgp    = (unsigned short*)(ws + 524288);

    conv_kernel<<<256, 256, 0, stream>>>(whh0, wih1, whh1, bih1, bhh1,
                                         whh0_b, wih1_b, whh1_b, bias1);
    xg_gemm<<<dim3(32, 16), 512, 0, stream>>>(x, wih0, bih0, bhh0, xgp);
    lstm_fused<<<32, 512, 0, stream>>>(whh0_b, wih1_b, whh1_b, bias1, xgp,
                                       (float*)d_out);
}

// Round 2
// 738.682 us; speedup vs baseline: 1.4562x; 1.4562x over previous
//
#include <hip/hip_runtime.h>
#include <cstdint>
#include <cstddef>

// LSTM B=256,S=512,C=64,H=128, 2 layers, gates i,f,g,o (torch order).
// Round 5: fused kernel (32 blocks x 512 threads), register-pressure fixed.
// Round-4 failure: VGPR_Count=128 < the 192 needed for weights -> compiler
// rematerialized weight loads from global EVERY step (~48 L2 loads/wave/step
// on the critical path, ~4400 cy/step). Fixes here:
//   1. Temporal phase split: L0 (MFMA+EW+write) fully before L1 -> a0/a1
//      accumulators never co-live (peak -16 VGPR).
//   2. L1's ih GEMM re-reads h0 from LDS (4 extra ds_read_b128/wave/step)
//      instead of holding h0 frags across phases (peak -16 VGPR).
//   3. Weight frags pinned with asm("":"+v") -> cannot be rematerialized.
//   4. A-frag don't-care rows ((r&3)>=2) read the SAME LDS address as the
//      valid lane below -> same-address broadcast, halves unique LDS bytes
//      and bank conflicts.
// Peak est: 192 weights + 16 acc + 16 frags + ~20 misc ~= 245 < 256 cap.
//
// MFMA 16x16x32 bf16 frags (verified rounds 1-4):
//   A[m=lane&15][k=(lane>>4)*8+j], B == W[n=lane&15][k] 16B row chunk,
//   D[m=4*(lane>>4)+reg][n=lane&15]
// Batch rows permuted into tile rows {m : (m&3)<2}: elementwise touches
// rr=0,1 only (2 rows/lane).

#define S_LEN 512
#define B_SZ  256
#define C_IN  64
#define HDIM  128
#define XG_TSTRIDE (32 * 512 * 8)   // shorts per timestep slot of xg

using short8  = __attribute__((ext_vector_type(8))) short;   // 8 bf16
using float4v = __attribute__((ext_vector_type(4))) float;

template<bool V> struct Flag { static constexpr bool value = V; };

__device__ __forceinline__ unsigned short f2b(float f) {
    union { float f; unsigned int u; } v; v.f = f;
    unsigned int u = v.u;
    return (unsigned short)((u + 0x7FFFu + ((u >> 16) & 1u)) >> 16);
}
__device__ __forceinline__ float b2f(unsigned short s) {
    union { unsigned int u; float f; } v; v.u = ((unsigned int)s) << 16;
    return v.f;
}
// lean activations: sigma = rcp(1+exp2(-x*log2e)), tanh = 1-2*rcp(1+exp2(2x*log2e))
__device__ __forceinline__ float sig_(float x) {
    return __builtin_amdgcn_rcpf(1.0f + __builtin_amdgcn_exp2f(x * -1.442695041f));
}
__device__ __forceinline__ float tanh_(float x) {
    return 1.0f - 2.0f * __builtin_amdgcn_rcpf(1.0f + __builtin_amdgcn_exp2f(x * 2.885390082f));
}
__device__ __forceinline__ short8 load8_f2b(const float* s) {
    const float4v f0 = *(const float4v*)s;
    const float4v f1 = *(const float4v*)(s + 4);
    short8 t;
#pragma unroll
    for (int e = 0; e < 4; ++e) {
        t[e]     = (short)f2b(f0[e]);
        t[e + 4] = (short)f2b(f1[e]);
    }
    return t;
}

// ---- weight conversion (fp32 -> bf16 B-frag-readable row-major) ----
__global__ void conv_kernel(const float* __restrict__ whh0,
                            const float* __restrict__ wih1, const float* __restrict__ whh1,
                            const float* __restrict__ bih1, const float* __restrict__ bhh1,
                            unsigned short* __restrict__ whh0_b, unsigned short* __restrict__ wih1_b,
                            unsigned short* __restrict__ whh1_b, float* __restrict__ bias1) {
    int i = blockIdx.x * blockDim.x + threadIdx.x;
    if (i < 4 * HDIM * HDIM) {
        whh0_b[i] = f2b(whh0[i]);
        wih1_b[i] = f2b(wih1[i]);
        whh1_b[i] = f2b(whh1[i]);
    }
    if (i < 4 * HDIM) bias1[i] = bih1[i] + bhh1[i];
}

// ---- hoisted L0 input GEMM: xg[t][blk][tid][8] = (x@Wih0^T + bih0 + bhh0),
//      packed per-lane in D-layout order [g*2+rr] so the recurrent kernel's
//      lane (same blk,tid mapping) loads its 8 acc-init values as one 16B read.
__global__ __launch_bounds__(512, 2)
void xg_gemm(const float* __restrict__ x, const float* __restrict__ wih0,
             const float* __restrict__ bih0, const float* __restrict__ bhh0,
             unsigned short* __restrict__ xg) {
    const int tid = threadIdx.x;
    const int w = tid >> 6, L = tid & 63, q = L >> 4, r = L & 15;
    const int blk = blockIdx.x, tch = blockIdx.y;
    const int boff = blk * 8, j = w * 16 + r;
    const int rowload = (r >> 2) * 2 + (r & 1);

    short8 wf[4][2]; float bias_s[4];
#pragma unroll
    for (int g = 0; g < 4; ++g) {
        const int nrow = g * HDIM + j;
#pragma unroll
        for (int kk = 0; kk < 2; ++kk)
            wf[g][kk] = load8_f2b(wih0 + (size_t)nrow * C_IN + kk * 32 + q * 8);
        bias_s[g] = bih0[nrow] + bhh0[nrow];
    }

    const float* px = x + ((size_t)(boff + rowload) * S_LEN + (size_t)tch * 32) * C_IN + q * 8;
    unsigned short* po = xg + ((size_t)(tch * 32) * 32 + blk) * 4096 + (size_t)tid * 8;

    for (int tt = 0; tt < 32; ++tt) {
        short8 xa[2];
#pragma unroll
        for (int kk = 0; kk < 2; ++kk) xa[kk] = load8_f2b(px + kk * 32);
        float4v a[4];
#pragma unroll
        for (int g = 0; g < 4; ++g) a[g] = (float4v){bias_s[g], bias_s[g], 0.f, 0.f};
#pragma unroll
        for (int kk = 0; kk < 2; ++kk)
#pragma unroll
            for (int g = 0; g < 4; ++g)
                a[g] = __builtin_amdgcn_mfma_f32_16x16x32_bf16(xa[kk], wf[g][kk], a[g], 0, 0, 0);
        short8 o;
#pragma unroll
        for (int g = 0; g < 4; ++g) {
            o[2 * g]     = (short)f2b(a[g][0]);
            o[2 * g + 1] = (short)f2b(a[g][1]);
        }
        *(short8*)po = o;
        px += C_IN;
        po += XG_TSTRIDE;
    }
}

// ---- fused 2-layer recurrence ----
__global__ __launch_bounds__(512, 2)
void lstm_fused(const unsigned short* __restrict__ whh0_b,
                const unsigned short* __restrict__ wih1_b,
                const unsigned short* __restrict__ whh1_b,
                const float* __restrict__ bias1,
                const unsigned short* __restrict__ xg,
                float* __restrict__ out) {
    // LDS: h0 double-buffer + h1 double-buffer, each 2048 shorts (16 rows x 128 cols)
    __shared__ __align__(16) unsigned short hbuf[4 * 2048];
    const int tid = threadIdx.x;
    const int w = tid >> 6, L = tid & 63, q = L >> 4, r = L & 15;
    const int blk = blockIdx.x;
    const int boff = blk * 8, j = w * 16 + r;

    // register-resident weights: 48 B-frags = 192 VGPRs, pinned against remat
    short8 whh0[4][4], wih1[4][4], whh1[4][4];
    float b1s[4];
#pragma unroll
    for (int g = 0; g < 4; ++g) {
        const size_t nrow = (size_t)(g * HDIM + j);
#pragma unroll
        for (int kk = 0; kk < 4; ++kk) {
            whh0[g][kk] = *(const short8*)(whh0_b + nrow * HDIM + kk * 32 + q * 8);
            wih1[g][kk] = *(const short8*)(wih1_b + nrow * HDIM + kk * 32 + q * 8);
            whh1[g][kk] = *(const short8*)(whh1_b + nrow * HDIM + kk * 32 + q * 8);
        }
        b1s[g] = bias1[g * HDIM + j];
    }
#pragma unroll
    for (int g = 0; g < 4; ++g) {
        asm volatile("" : "+v"(whh0[g][0]), "+v"(whh0[g][1]), "+v"(whh0[g][2]), "+v"(whh0[g][3]));
        asm volatile("" : "+v"(wih1[g][0]), "+v"(wih1[g][1]), "+v"(wih1[g][2]), "+v"(wih1[g][3]));
        asm volatile("" : "+v"(whh1[g][0]), "+v"(whh1[g][1]), "+v"(whh1[g][2]), "+v"(whh1[g][3]));
    }

    for (int idx = tid; idx < 4 * 1024; idx += 512) ((unsigned int*)hbuf)[idx] = 0u;

    float cf0[2] = {0.f, 0.f}, cf1[2] = {0.f, 0.f};
    // A-frag read: don't-care rows ((r&3)>=2) redirect to the valid row two
    // below -> same-address broadcast (free), halves unique LDS traffic.
    const int rred = ((r & 3) < 2) ? r : (r - 2);
    const int rdoff = q * 128 + rred * 8;               // + kk*512 per K-chunk
    const int chunkbase = (j >> 3) * 128 + (j & 7);     // h write slot (col-chunk layout)
    float* fout = out + (size_t)(boff + 2 * q) * HDIM + j;

    const unsigned short* pxg = xg + (size_t)blk * 4096 + (size_t)tid * 8;
    short8 xgA = *(const short8*)pxg;   // xg[t=0]
    pxg += XG_TSTRIDE;
    short8 xgB;

    __syncthreads();    // covers LDS zero + weight/xg load drain (once, cold)

    // iteration k: L0 h0_k (if D0) THEN L1 h1_{k-1} (if D1); both read only
    // previous-iteration buffers r0/r1, write w0/w1.
    auto step = [&](auto D0_, auto D1_, auto FIN_,
                    unsigned short* r0, unsigned short* w0,
                    unsigned short* r1, unsigned short* w1,
                    short8& xc, short8& xn) {
        constexpr bool D0  = decltype(D0_)::value;
        constexpr bool D1  = decltype(D1_)::value;
        constexpr bool FIN = decltype(FIN_)::value;

        if constexpr (!FIN) {            // prefetch next xg (vmcnt load, spans the barrier)
            xn = *(const short8*)pxg;
            pxg += XG_TSTRIDE;
        }

        if constexpr (D0) {
            float4v a0[4];
#pragma unroll
            for (int g = 0; g < 4; ++g)
                a0[g] = (float4v){b2f((unsigned short)xc[2 * g]),
                                  b2f((unsigned short)xc[2 * g + 1]), 0.f, 0.f};
#pragma unroll
            for (int kk = 0; kk < 4; ++kk) {
                const short8 h0f = *(const short8*)(r0 + kk * 512 + rdoff);
#pragma unroll
                for (int g = 0; g < 4; ++g)
                    a0[g] = __builtin_amdgcn_mfma_f32_16x16x32_bf16(h0f, whh0[g][kk], a0[g], 0, 0, 0);
            }
#pragma unroll
            for (int rr = 0; rr < 2; ++rr) {
                const float iv = sig_(a0[0][rr]);
                const float fv = sig_(a0[1][rr]);
                const float gv = tanh_(a0[2][rr]);
                const float ov = sig_(a0[3][rr]);
                cf0[rr] = fv * cf0[rr] + iv * gv;
                w0[chunkbase + (4 * q + rr) * 8] = f2b(ov * tanh_(cf0[rr]));
            }
        }

        if constexpr (D1) {
            float4v a1[4];
#pragma unroll
            for (int g = 0; g < 4; ++g) a1[g] = (float4v){b1s[g], b1s[g], 0.f, 0.f};
            // ih: input = h0_{k-1} (re-read from r0; broadcast-redirected rows)
#pragma unroll
            for (int kk = 0; kk < 4; ++kk) {
                const short8 hif = *(const short8*)(r0 + kk * 512 + rdoff);
#pragma unroll
                for (int g = 0; g < 4; ++g)
                    a1[g] = __builtin_amdgcn_mfma_f32_16x16x32_bf16(hif, wih1[g][kk], a1[g], 0, 0, 0);
            }
            // hh: h1_{k-2}
#pragma unroll
            for (int kk = 0; kk < 4; ++kk) {
                const short8 h1f = *(const short8*)(r1 + kk * 512 + rdoff);
#pragma unroll
                for (int g = 0; g < 4; ++g)
                    a1[g] = __builtin_amdgcn_mfma_f32_16x16x32_bf16(h1f, whh1[g][kk], a1[g], 0, 0, 0);
            }
#pragma unroll
            for (int rr = 0; rr < 2; ++rr) {
                const float iv = sig_(a1[0][rr]);
                const float fv = sig_(a1[1][rr]);
                const float gv = tanh_(a1[2][rr]);
                const float ov = sig_(a1[3][rr]);
                cf1[rr] = fv * cf1[rr] + iv * gv;
                const float hv = ov * tanh_(cf1[rr]);
                if constexpr (FIN) fout[rr * HDIM] = hv;
                else w1[chunkbase + (4 * q + rr) * 8] = f2b(hv);
            }
        }

        // lgkm-only barrier: h_t visible, but vmcnt (xg prefetch) stays in flight
        if constexpr (!FIN)
            asm volatile("s_waitcnt lgkmcnt(0)\n\ts_barrier" ::: "memory");
    };

    unsigned short* h0A = hbuf;
    unsigned short* h0B = hbuf + 2048;
    unsigned short* h1A = hbuf + 4096;
    unsigned short* h1B = hbuf + 6144;
    using T = Flag<true>; using F = Flag<false>;

    step(T{}, F{}, F{}, h0A, h0B, h1A, h1B, xgA, xgB);      // k=0: L0 only
#pragma unroll 1
    for (int k = 0; k < 255; ++k) {                          // k=1..510
        step(T{}, T{}, F{}, h0B, h0A, h1B, h1A, xgB, xgA);
        step(T{}, T{}, F{}, h0A, h0B, h1A, h1B, xgA, xgB);
    }
    step(T{}, T{}, F{}, h0B, h0A, h1B, h1A, xgB, xgA);      // k=511
    step(F{}, T{}, T{}, h0A, h0B, h1A, h1B, xgA, xgB);      // k=512: L1 only -> out
}

// ---- workspace layout (bytes) ----
//        0 : whh0_b 131072
//   131072 : wih1_b 131072
//   262144 : whh1_b 131072
//   393216 : bias1    2048
//   524288 : xg   134742016   ((S_LEN+2) t-slots: 2 pad slots for tail prefetch)
// total ~135.3 MB

extern "C" void kernel_launch(void* const* d_in, const int* in_sizes, int n_in,
                              void* d_out, int out_size, void* d_ws, size_t ws_size,
                              hipStream_t stream) {
    const float* x    = (const float*)d_in[0];
    const float* wih0 = (const float*)d_in[1];
    const float* whh0 = (const float*)d_in[2];
    const float* bih0 = (const float*)d_in[3];
    const float* bhh0 = (const float*)d_in[4];
    const float* wih1 = (const float*)d_in[5];
    const float* whh1 = (const float*)d_in[6];
    const float* bih1 = (const float*)d_in[7];
    const float* bhh1 = (const float*)d_in[8];

    char* ws = (char*)d_ws;
    unsigned short* whh0_b = (unsigned short*)(ws + 0);
    unsigned short* wih1_b = (unsigned short*)(ws + 131072);
    unsigned short* whh1_b = (unsigned short*)(ws + 262144);
    float*          bias1  = (float*)(ws + 393216);
    unsigned short* xgp    = (unsigned short*)(ws + 524288);

    conv_kernel<<<256, 256, 0, stream>>>(whh0, wih1, whh1, bih1, bhh1,
                                         whh0_b, wih1_b, whh1_b, bias1);
    xg_gemm<<<dim3(32, 16), 512, 0, stream>>>(x, wih0, bih0, bhh0, xgp);
    lstm_fused<<<32, 512, 0, stream>>>(whh0_b, wih1_b, whh1_b, bias1, xgp,
                                       (float*)d_out);
}